// Round 1
// baseline (32.012 us; speedup 1.0000x reference)
//
#include <hip/hip_runtime.h>
#include <hip/hip_bf16.h>

typedef __attribute__((ext_vector_type(8))) short bf16x8;
typedef __attribute__((ext_vector_type(4))) float f32x4;

static constexpr int Bb = 64;
static constexpr int Qq = 32;
static constexpr int LD = 4096;
static constexpr int Dd = 128;
static constexpr int SPLITS = 8;           // L-chunks per batch -> 512 blocks
static constexpr int CHUNK = LD / SPLITS;  // 512 tokens per block
static constexpr int NWAVE = 4;            // 256 threads
static constexpr int TPW = CHUNK / NWAVE;  // 128 tokens per wave
static constexpr int LTILES = TPW / 16;    // 8 MFMA l-tiles per wave

__device__ __forceinline__ short f2bf(float f) {
  __hip_bfloat16 h = __float2bfloat16(f);
  return *reinterpret_cast<short*>(&h);
}

// Load 8 consecutive floats and pack to bf16x8 (one MFMA operand register set).
__device__ __forceinline__ bf16x8 pack8(const float* __restrict__ src) {
  float4 f0 = *reinterpret_cast<const float4*>(src);
  float4 f1 = *reinterpret_cast<const float4*>(src + 4);
  bf16x8 v;
  v[0] = f2bf(f0.x); v[1] = f2bf(f0.y); v[2] = f2bf(f0.z); v[3] = f2bf(f0.w);
  v[4] = f2bf(f1.x); v[5] = f2bf(f1.y); v[6] = f2bf(f1.z); v[7] = f2bf(f1.w);
  return v;
}

// Stage 1: per (batch, L-chunk) block compute partial max over the chunk for
// each of the 32 query tokens. pmax layout: [B][SPLITS][32] fp32.
__global__ __launch_bounds__(256) void maxsim_stage1(
    const float* __restrict__ qe, const float* __restrict__ de,
    float* __restrict__ pmax) {
  const int blk  = blockIdx.x;
  const int b    = blk / SPLITS;
  const int s    = blk % SPLITS;
  const int wave = threadIdx.x >> 6;
  const int lane = threadIdx.x & 63;
  const int lcol = lane & 15;   // MFMA column slot (doc token within tile / q row for A)
  const int lgrp = lane >> 4;   // MFMA k-group

  const float* __restrict__ qb = qe + (size_t)b * Qq * Dd;
  const float* __restrict__ db = de + (size_t)b * LD * Dd;

  // A fragments (query tile, M=32 -> 2 M-tiles of 16), held in registers for
  // the whole kernel. A[m][k]: m = lcol, k = lgrp*8 + j (same lane->k rule as
  // B, so any k-slot permutation cancels in the dot product).
  bf16x8 afrag[2][4];
#pragma unroll
  for (int mt = 0; mt < 2; ++mt)
#pragma unroll
    for (int kb = 0; kb < 4; ++kb)
      afrag[mt][kb] = pack8(qb + (size_t)(mt * 16 + lcol) * Dd + kb * 32 + lgrp * 8);

  float mx0[4], mx1[4];
#pragma unroll
  for (int i = 0; i < 4; ++i) { mx0[i] = -3.4e38f; mx1[i] = -3.4e38f; }

  const int tok0 = s * CHUNK + wave * TPW;
  for (int lt = 0; lt < LTILES; ++lt) {
    const float* __restrict__ trow = db + (size_t)(tok0 + lt * 16 + lcol) * Dd;
    f32x4 acc0 = {0.f, 0.f, 0.f, 0.f};
    f32x4 acc1 = {0.f, 0.f, 0.f, 0.f};
#pragma unroll
    for (int kb = 0; kb < 4; ++kb) {
      bf16x8 bfrag = pack8(trow + kb * 32 + lgrp * 8);
      acc0 = __builtin_amdgcn_mfma_f32_16x16x32_bf16(afrag[0][kb], bfrag, acc0, 0, 0, 0);
      acc1 = __builtin_amdgcn_mfma_f32_16x16x32_bf16(afrag[1][kb], bfrag, acc1, 0, 0, 0);
    }
    // C/D layout (m89-verified): col = lane&15 (doc token), row = lgrp*4 + i (query).
#pragma unroll
    for (int i = 0; i < 4; ++i) {
      mx0[i] = fmaxf(mx0[i], acc0[i]);
      mx1[i] = fmaxf(mx1[i], acc1[i]);
    }
  }

  // Max over doc-token columns = butterfly over the low 4 lane bits.
#pragma unroll
  for (int off = 1; off < 16; off <<= 1) {
#pragma unroll
    for (int i = 0; i < 4; ++i) {
      mx0[i] = fmaxf(mx0[i], __shfl_xor(mx0[i], off));
      mx1[i] = fmaxf(mx1[i], __shfl_xor(mx1[i], off));
    }
  }

  __shared__ float smax[NWAVE][Qq];
  if (lcol == 0) {
#pragma unroll
    for (int i = 0; i < 4; ++i) {
      smax[wave][lgrp * 4 + i]      = mx0[i];
      smax[wave][16 + lgrp * 4 + i] = mx1[i];
    }
  }
  __syncthreads();
  if (threadIdx.x < Qq) {
    const int qi = threadIdx.x;
    float m = fmaxf(fmaxf(smax[0][qi], smax[1][qi]),
                    fmaxf(smax[2][qi], smax[3][qi]));
    pmax[((size_t)b * SPLITS + s) * Qq + qi] = m;
  }
}

// Stage 2: out[b] = sum_q max_s pmax[b][s][q]. One wave per batch.
__global__ __launch_bounds__(64) void maxsim_stage2(
    const float* __restrict__ pmax, float* __restrict__ out) {
  const int b = blockIdx.x;
  const int lane = threadIdx.x;
  float v = 0.f;
  if (lane < Qq) {
    float m = -3.4e38f;
#pragma unroll
    for (int s = 0; s < SPLITS; ++s)
      m = fmaxf(m, pmax[((size_t)b * SPLITS + s) * Qq + lane]);
    v = m;
  }
#pragma unroll
  for (int off = 1; off < 64; off <<= 1) v += __shfl_xor(v, off);
  if (lane == 0) out[b] = v;
}

extern "C" void kernel_launch(void* const* d_in, const int* in_sizes, int n_in,
                              void* d_out, int out_size, void* d_ws, size_t ws_size,
                              hipStream_t stream) {
  const float* qe = (const float*)d_in[0];  // [64,32,128] f32
  const float* de = (const float*)d_in[1];  // [64,4096,128] f32
  float* out  = (float*)d_out;              // [64] f32
  float* pmax = (float*)d_ws;               // [64][8][32] f32 = 64 KB scratch

  maxsim_stage1<<<Bb * SPLITS, 256, 0, stream>>>(qe, de, pmax);
  maxsim_stage2<<<Bb, 64, 0, stream>>>(pmax, out);
}